// Round 1
// baseline (338.810 us; speedup 1.0000x reference)
//
#include <hip/hip_runtime.h>

typedef _Float16 f16;
typedef _Float16 f16x8 __attribute__((ext_vector_type(8)));
typedef _Float16 f16x4v __attribute__((ext_vector_type(4)));
typedef float f32x4 __attribute__((ext_vector_type(4)));

#define DEVINL __device__ __forceinline__

DEVINL void gload16(const void* g, void* l) {
  __builtin_amdgcn_global_load_lds(
      (const __attribute__((address_space(1))) void*)g,
      (__attribute__((address_space(3))) void*)l, 16, 0, 0);
}

// ---------------------------------------------------------------------------
// W_effT[n][k] = (W[k][n] + sum_r la[k][r]*lb[r][n]) * (n < scaleCols ? 0.125 : 1)
// fp32 math, fp16 store, transposed for both-row-major MFMA fragment reads.
// grid: (N/64, K/64), 256 threads.
// ---------------------------------------------------------------------------
__global__ __launch_bounds__(256) void weff_kernel(
    const float* __restrict__ W, const float* __restrict__ la,
    const float* __restrict__ lb, f16* __restrict__ WT,
    int N, int K, int scaleCols)
{
  __shared__ float T[64][65];
  __shared__ float La[64][33];
  __shared__ float Lb[32][65];
  int n0 = blockIdx.x * 64, k0 = blockIdx.y * 64;
  int t = threadIdx.x;
  for (int i = 0; i < 16; ++i) {
    int idx = i * 256 + t; int kk = idx >> 6, nn = idx & 63;
    T[nn][kk] = W[(size_t)(k0 + kk) * N + n0 + nn];
  }
  for (int i = 0; i < 8; ++i) {
    int idx = i * 256 + t; int kk = idx >> 5, rr = idx & 31;
    La[kk][rr] = la[(size_t)(k0 + kk) * 32 + rr];
  }
  for (int i = 0; i < 8; ++i) {
    int idx = i * 256 + t; int rr = idx >> 6, nn = idx & 63;
    Lb[rr][nn] = lb[(size_t)rr * N + n0 + nn];
  }
  __syncthreads();
  for (int i = 0; i < 16; ++i) {
    int idx = i * 256 + t; int nn = idx >> 6, kk = idx & 63;
    float acc = T[nn][kk];
    #pragma unroll
    for (int r = 0; r < 32; ++r) acc += La[kk][r] * Lb[r][nn];
    if (n0 + nn < scaleCols) acc *= 0.125f;
    WT[(size_t)(n0 + nn) * K + k0 + kk] = (f16)acc;
  }
}

// ---------------------------------------------------------------------------
__global__ __launch_bounds__(256) void cvt_f32_f16(const float* __restrict__ in,
                                                   f16* __restrict__ out)
{
  int i = (blockIdx.x * 256 + threadIdx.x) * 4;
  float4 v = *(const float4*)(in + i);
  f16x4v o = {(f16)v.x, (f16)v.y, (f16)v.z, (f16)v.w};
  *(f16x4v*)(out + i) = o;
}

// ---------------------------------------------------------------------------
// mask dtype is ambiguous (np.bool_ uint8 vs int32). Detect: in int32 layout
// of 0/1 values every byte at offset %4 != 0 is zero; in uint8 layout ~half of
// them are 1. Canonicalize to uint8[B*512] (only first S=512 keys used).
// ---------------------------------------------------------------------------
__global__ __launch_bounds__(256) void mask_canon(const unsigned char* __restrict__ m,
                                                  unsigned char* __restrict__ out)
{
  __shared__ int flag;
  if (threadIdx.x == 0) flag = 0;
  __syncthreads();
  int found = 0;
  for (int p = threadIdx.x; p < 12288; p += 256)
    if ((p & 3) && m[p]) found = 1;
  if (found) flag = 1;
  __syncthreads();
  int u8 = flag;
  const int* mi = (const int*)m;
  for (int idx = threadIdx.x; idx < 4096; idx += 256) {
    int b = idx >> 9, k = idx & 511;
    int v = u8 ? (int)m[b * 1536 + k] : mi[b * 1536 + k];
    out[idx] = (unsigned char)(v != 0);
  }
}

// ---------------------------------------------------------------------------
// 128x128 GEMM, BK=32, 4 waves (2x2 of 64x64), mfma_f32_16x16x32_f16.
// C[m][n] = A[m][:] . Bt[n][:]   (A: MxK row-major f16, Bt: NxK row-major f16)
// EPI 0: scatter qkv -> Q[b,h,s,d], K[b,h,s,d], Vt[b,h,d,s]
// EPI 1: +bias, exact GELU, f16 out
// EPI 2: +bias, +residual(f16), f16 out
// EPI 3: +bias, fp32 out
// ---------------------------------------------------------------------------
template <int EPI>
__global__ __launch_bounds__(256) void gemm128(
    const f16* __restrict__ A, const f16* __restrict__ Bt,
    int M, int N, int K,
    const float* __restrict__ bias, const f16* __restrict__ resid,
    f16* __restrict__ outH, float* __restrict__ outF,
    f16* __restrict__ Qo, f16* __restrict__ Ko, f16* __restrict__ Vto)
{
  __shared__ __align__(16) f16 As[128 * 32];
  __shared__ __align__(16) f16 Bs[128 * 32];
  int tid = threadIdx.x, wid = tid >> 6, l = tid & 63;
  int lg = l >> 4, lr = l & 15;
  int bm = blockIdx.x * 128, bn = blockIdx.y * 128;
  int wr = (wid >> 1) * 64, wc = (wid & 1) * 64;
  f32x4 acc[4][4] = {};

  const f16* gA = A + (size_t)(bm + wid * 16 + (l >> 2)) * K + (l & 3) * 8;
  const f16* gB = Bt + (size_t)(bn + wid * 16 + (l >> 2)) * K + (l & 3) * 8;
  f16* lA = As + wid * 16 * 32;   // wave-uniform LDS base; HW adds lane*16B
  f16* lB = Bs + wid * 16 * 32;

  for (int k0 = 0; k0 < K; k0 += 32) {
    __syncthreads();
    gload16(gA + k0, lA);
    gload16(gA + (size_t)64 * K + k0, lA + 64 * 32);
    gload16(gB + k0, lB);
    gload16(gB + (size_t)64 * K + k0, lB + 64 * 32);
    __syncthreads();
    f16x8 af[4], bf[4];
    #pragma unroll
    for (int i = 0; i < 4; ++i)
      af[i] = *(const f16x8*)(As + (wr + i * 16 + lr) * 32 + lg * 8);
    #pragma unroll
    for (int j = 0; j < 4; ++j)
      bf[j] = *(const f16x8*)(Bs + (wc + j * 16 + lr) * 32 + lg * 8);
    #pragma unroll
    for (int i = 0; i < 4; ++i)
      #pragma unroll
      for (int j = 0; j < 4; ++j)
        acc[i][j] = __builtin_amdgcn_mfma_f32_16x16x32_f16(af[i], bf[j], acc[i][j], 0, 0, 0);
  }

  #pragma unroll
  for (int i = 0; i < 4; ++i) {
    #pragma unroll
    for (int j = 0; j < 4; ++j) {
      int n = bn + wc + j * 16 + lr;
      float bv = (EPI >= 1) ? bias[n] : 0.0f;
      #pragma unroll
      for (int r = 0; r < 4; ++r) {
        int m = bm + wr + i * 16 + lg * 4 + r;
        float v = acc[i][j][r];
        if (EPI == 0) {
          int bb = m >> 9, ss = m & 511;
          int which = n >> 10, c = n & 1023, hh = c >> 6, dd = c & 63;
          size_t base = (size_t)(bb * 16 + hh);
          if (which == 0)      Qo[(base * 512 + ss) * 64 + dd] = (f16)v;
          else if (which == 1) Ko[(base * 512 + ss) * 64 + dd] = (f16)v;
          else                 Vto[(base * 64 + dd) * 512 + ss] = (f16)v;
        } else if (EPI == 1) {
          v += bv;
          v = 0.5f * v * (1.0f + erff(v * 0.70710678118654752f));
          outH[(size_t)m * N + n] = (f16)v;
        } else if (EPI == 2) {
          v += bv + (float)resid[(size_t)m * N + n];
          outH[(size_t)m * N + n] = (f16)v;
        } else {
          outF[(size_t)m * N + n] = v + bv;
        }
      }
    }
  }
}

// ---------------------------------------------------------------------------
// Flash attention. block = (qblk in 0..3, bh in 0..127), 4 waves x 32 q-rows.
// Q[b,h,s,d] f16 (scale already folded), K[b,h,s,d] f16, Vt[b,h,d,s] f16.
// K/V tiles of 128 staged in LDS; Q frags straight from global (read once).
// Online softmax; P goes through wave-private LDS for A-operand layout.
// Writes XO[b, s, h*64+d] f16.
// ---------------------------------------------------------------------------
__global__ __launch_bounds__(256) void attn_kernel(
    const f16* __restrict__ Q, const f16* __restrict__ Kc,
    const f16* __restrict__ Vt, const unsigned char* __restrict__ cmask,
    f16* __restrict__ XO)
{
  __shared__ __align__(16) f16 Ks[128 * 64];   // [krow][d]     16 KB
  __shared__ __align__(16) f16 Vs[64 * 128];   // [d][krow]     16 KB
  __shared__ __align__(16) f16 Ps[4 * 32 * 128]; // per-wave P  32 KB
  int tid = threadIdx.x, w = tid >> 6, l = tid & 63;
  int lg = l >> 4, lr = l & 15;
  int qblk = blockIdx.x, bh = blockIdx.y;
  int b = bh >> 4, h = bh & 15;
  const f16* Qg = Q + (size_t)bh * 512 * 64 + qblk * 128 * 64;
  const f16* Kg = Kc + (size_t)bh * 512 * 64;
  const f16* Vg = Vt + (size_t)bh * 64 * 512;
  const unsigned char* mb = cmask + b * 512;

  // Q fragments: wave w owns q-rows w*32 .. w*32+31 of this 128-row block
  f16x8 qf[2][2];
  #pragma unroll
  for (int i = 0; i < 2; ++i)
    #pragma unroll
    for (int kc = 0; kc < 2; ++kc)
      qf[i][kc] = *(const f16x8*)(Qg + (size_t)(w * 32 + i * 16 + lr) * 64 + kc * 32 + lg * 8);

  f32x4 O[2][4] = {};
  float mrow[2][4], lrow[2][4];
  #pragma unroll
  for (int i = 0; i < 2; ++i)
    #pragma unroll
    for (int r = 0; r < 4; ++r) { mrow[i][r] = -1e30f; lrow[i][r] = 0.0f; }

  f16* Pw = Ps + w * 32 * 128;

  for (int kt = 0; kt < 4; ++kt) {
    __syncthreads();  // all waves done reading prior K/V tile
    #pragma unroll
    for (int is = 0; is < 4; ++is)
      gload16(Kg + (size_t)(kt * 128 + is * 32 + w * 8 + (l >> 3)) * 64 + (l & 7) * 8,
              Ks + (is * 32 + w * 8) * 64);
    #pragma unroll
    for (int is = 0; is < 4; ++is)
      gload16(Vg + (size_t)(is * 16 + w * 4 + lg) * 512 + kt * 128 + lr * 8,
              Vs + (is * 16 + w * 4) * 128);
    __syncthreads();

    // S = Q K^T  (32q x 128k per wave)
    f32x4 sc[2][8] = {};
    #pragma unroll
    for (int j = 0; j < 8; ++j) {
      f16x8 kf0 = *(const f16x8*)(Ks + (j * 16 + lr) * 64 + lg * 8);
      f16x8 kf1 = *(const f16x8*)(Ks + (j * 16 + lr) * 64 + 32 + lg * 8);
      sc[0][j] = __builtin_amdgcn_mfma_f32_16x16x32_f16(qf[0][0], kf0, sc[0][j], 0, 0, 0);
      sc[0][j] = __builtin_amdgcn_mfma_f32_16x16x32_f16(qf[0][1], kf1, sc[0][j], 0, 0, 0);
      sc[1][j] = __builtin_amdgcn_mfma_f32_16x16x32_f16(qf[1][0], kf0, sc[1][j], 0, 0, 0);
      sc[1][j] = __builtin_amdgcn_mfma_f32_16x16x32_f16(qf[1][1], kf1, sc[1][j], 0, 0, 0);
    }
    // mask (per k-column)
    bool keep[8];
    #pragma unroll
    for (int j = 0; j < 8; ++j) keep[j] = mb[kt * 128 + j * 16 + lr] != 0;
    #pragma unroll
    for (int i = 0; i < 2; ++i)
      #pragma unroll
      for (int j = 0; j < 8; ++j)
        #pragma unroll
        for (int r = 0; r < 4; ++r)
          sc[i][j][r] = keep[j] ? sc[i][j][r] : -1e30f;

    // online softmax: rows live in 16-lane groups (row = lg*4+r)
    #pragma unroll
    for (int i = 0; i < 2; ++i) {
      #pragma unroll
      for (int r = 0; r < 4; ++r) {
        float pm = sc[i][0][r];
        #pragma unroll
        for (int j = 1; j < 8; ++j) pm = fmaxf(pm, sc[i][j][r]);
        pm = fmaxf(pm, __shfl_xor(pm, 1));
        pm = fmaxf(pm, __shfl_xor(pm, 2));
        pm = fmaxf(pm, __shfl_xor(pm, 4));
        pm = fmaxf(pm, __shfl_xor(pm, 8));
        float mn = fmaxf(mrow[i][r], pm);
        float alpha = __expf(mrow[i][r] - mn);
        mrow[i][r] = mn;
        lrow[i][r] *= alpha;
        #pragma unroll
        for (int jd = 0; jd < 4; ++jd) O[i][jd][r] *= alpha;
      }
    }
    // P = exp(S-m): accumulate row sums, stash f16 P in wave-private LDS
    #pragma unroll
    for (int i = 0; i < 2; ++i) {
      float rs[4] = {0.f, 0.f, 0.f, 0.f};
      #pragma unroll
      for (int j = 0; j < 8; ++j)
        #pragma unroll
        for (int r = 0; r < 4; ++r) {
          float p = __expf(sc[i][j][r] - mrow[i][r]);
          rs[r] += p;
          Pw[(i * 16 + lg * 4 + r) * 128 + j * 16 + lr] = (f16)p;
        }
      #pragma unroll
      for (int r = 0; r < 4; ++r) {
        float s = rs[r];
        s += __shfl_xor(s, 1); s += __shfl_xor(s, 2);
        s += __shfl_xor(s, 4); s += __shfl_xor(s, 8);
        lrow[i][r] += s;
      }
    }
    // O += P @ V   (wave-private LDS, no barrier needed; compiler inserts lgkmcnt)
    #pragma unroll
    for (int kk = 0; kk < 4; ++kk) {
      f16x8 pa0 = *(const f16x8*)(Pw + lr * 128 + kk * 32 + lg * 8);
      f16x8 pa1 = *(const f16x8*)(Pw + (16 + lr) * 128 + kk * 32 + lg * 8);
      #pragma unroll
      for (int jd = 0; jd < 4; ++jd) {
        f16x8 vb = *(const f16x8*)(Vs + (jd * 16 + lr) * 128 + kk * 32 + lg * 8);
        O[0][jd] = __builtin_amdgcn_mfma_f32_16x16x32_f16(pa0, vb, O[0][jd], 0, 0, 0);
        O[1][jd] = __builtin_amdgcn_mfma_f32_16x16x32_f16(pa1, vb, O[1][jd], 0, 0, 0);
      }
    }
  }

  #pragma unroll
  for (int i = 0; i < 2; ++i)
    #pragma unroll
    for (int r = 0; r < 4; ++r) {
      int q = qblk * 128 + w * 32 + i * 16 + lg * 4 + r;
      float inv = 1.0f / lrow[i][r];
      #pragma unroll
      for (int jd = 0; jd < 4; ++jd) {
        int c = h * 64 + jd * 16 + lr;
        XO[((size_t)b * 512 + q) * 1024 + c] = (f16)(O[i][jd][r] * inv);
      }
    }
}

// ---------------------------------------------------------------------------
extern "C" void kernel_launch(void* const* d_in, const int* in_sizes, int n_in,
                              void* d_out, int out_size, void* d_ws, size_t ws_size,
                              hipStream_t stream)
{
  (void)in_sizes; (void)n_in; (void)out_size; (void)ws_size;
  const float* x            = (const float*)d_in[0];
  const unsigned char* mask = (const unsigned char*)d_in[1];
  const float* qkv_w   = (const float*)d_in[2];
  const float* qkv_la  = (const float*)d_in[3];
  const float* qkv_lb  = (const float*)d_in[4];
  const float* proj_w  = (const float*)d_in[5];
  const float* proj_b  = (const float*)d_in[6];
  const float* proj_la = (const float*)d_in[7];
  const float* proj_lb = (const float*)d_in[8];
  const float* fc1_w   = (const float*)d_in[9];
  const float* fc1_b   = (const float*)d_in[10];
  const float* fc1_la  = (const float*)d_in[11];
  const float* fc1_lb  = (const float*)d_in[12];
  const float* fc2_w   = (const float*)d_in[13];
  const float* fc2_b   = (const float*)d_in[14];
  const float* fc2_la  = (const float*)d_in[15];
  const float* fc2_lb  = (const float*)d_in[16];
  float* out = (float*)d_out;

  f16* p = (f16*)d_ws;
  f16* WqkvT = p; p += 3072 * 1024;
  f16* W1T   = p; p += 1024 * 1024;
  f16* W2T   = p; p += 1024 * 1024;
  f16* WpT   = p; p += 1024 * 1024;
  f16* Xh    = p; p += 4096 * 1024;   // reused as XO2 after GEMM1
  f16* Qb    = p; p += 128 * 512 * 64; // reused as H after attn
  f16* Kb    = p; p += 128 * 512 * 64;
  f16* Vt    = p; p += 128 * 64 * 512;
  f16* XO    = p; p += 4096 * 1024;
  unsigned char* cmask = (unsigned char*)p;
  f16* Hb  = Qb;   // Q dead after attn
  f16* XO2 = Xh;   // Xh dead after GEMM1

  weff_kernel<<<dim3(48, 16), 256, 0, stream>>>(qkv_w, qkv_la, qkv_lb, WqkvT, 3072, 1024, 1024);
  weff_kernel<<<dim3(16, 16), 256, 0, stream>>>(fc1_w, fc1_la, fc1_lb, W1T, 1024, 1024, 0);
  weff_kernel<<<dim3(16, 16), 256, 0, stream>>>(fc2_w, fc2_la, fc2_lb, W2T, 1024, 1024, 0);
  weff_kernel<<<dim3(16, 16), 256, 0, stream>>>(proj_w, proj_la, proj_lb, WpT, 1024, 1024, 0);
  cvt_f32_f16<<<4096, 256, 0, stream>>>(x, Xh);
  mask_canon<<<1, 256, 0, stream>>>(mask, cmask);

  gemm128<0><<<dim3(32, 24), 256, 0, stream>>>(Xh, WqkvT, 4096, 3072, 1024,
      nullptr, nullptr, nullptr, nullptr, Qb, Kb, Vt);
  attn_kernel<<<dim3(4, 128), 256, 0, stream>>>(Qb, Kb, Vt, cmask, XO);
  gemm128<1><<<dim3(32, 8), 256, 0, stream>>>(XO, W1T, 4096, 1024, 1024,
      fc1_b, nullptr, Hb, nullptr, nullptr, nullptr, nullptr);
  gemm128<2><<<dim3(32, 8), 256, 0, stream>>>(Hb, W2T, 4096, 1024, 1024,
      fc2_b, XO, XO2, nullptr, nullptr, nullptr, nullptr);
  gemm128<3><<<dim3(32, 8), 256, 0, stream>>>(XO2, WpT, 4096, 1024, 1024,
      proj_b, nullptr, nullptr, out, nullptr, nullptr, nullptr);
}